// Round 4
// baseline (278.486 us; speedup 1.0000x reference)
//
#include <hip/hip_runtime.h>

#define N 8192
#define D 256
#define NRB 128        // number of 64-row blocks
#define NU 8256        // NRB*(NRB+1)/2 upper-triangular 64x64 units
#define UPW 2          // units per wave (consecutive -> same row-block, A reused)

typedef short short8 __attribute__((ext_vector_type(8)));
typedef float f32x4 __attribute__((ext_vector_type(4)));

__device__ __forceinline__ unsigned short f2bf(float f) {
    unsigned int u = __float_as_uint(f);
    u += 0x7fffu + ((u >> 16) & 1u);   // RNE
    return (unsigned short)(u >> 16);
}
__device__ __forceinline__ float bf2f(unsigned short h) {
    return __uint_as_float(((unsigned int)h) << 16);
}

// Kernel 0: fp32 -> bf16 pre-conversion + row squared norms (of bf16-rounded
// values, consistent with the MFMA Gram) + zero the S/L accumulators.
__global__ __launch_bounds__(256) void k_cvt(const float* __restrict__ x,
                                             unsigned short* __restrict__ xb,
                                             float* __restrict__ sq,
                                             float* __restrict__ Sarr,
                                             float* __restrict__ Larr) {
    const int wv = threadIdx.x >> 6, lane = threadIdx.x & 63;
    const int row = blockIdx.x * 4 + wv;
    const float4 v = ((const float4*)x)[(size_t)row * 64 + lane];
    unsigned short pa = f2bf(v.x), pb = f2bf(v.y), pc = f2bf(v.z), pd = f2bf(v.w);
    float a = bf2f(pa), b = bf2f(pb), c = bf2f(pc), d = bf2f(pd);
    float s = a * a + b * b + c * c + d * d;
    ((ushort4*)xb)[(size_t)row * 64 + lane] = make_ushort4(pa, pb, pc, pd);
#pragma unroll
    for (int m = 1; m < 64; m <<= 1) s += __shfl_xor(s, m, 64);
    if (lane == 0) {
        sq[row] = s;
        Sarr[row] = 0.0f;
        Larr[row] = 0.0f;
    }
}

// Kernel 1: barrier-free symmetric Gram. Each WAVE independently processes
// UPW consecutive 64x64 upper-triangular units (i<=j in 64-row blocks).
// A (64 rows x K=256) lives in 128 VGPRs, reused while the row-block i is
// unchanged; B-fragments are read directly from L2 (same lane layout as A —
// verified rounds 1-3), interleaved with MFMA by the compiler (no barriers,
// no LDS, vmcnt-scheduled). Off-diagonal units commit row AND col sums
// (symmetry); diagonal units commit rows only. ln k = -d2/2T^2 (no log).
__global__ __launch_bounds__(256, 2) void k_gram(const unsigned short* __restrict__ xb,
                                                 const float* __restrict__ sq,
                                                 const float* __restrict__ temp,
                                                 float* __restrict__ Sarr,
                                                 float* __restrict__ Larr) {
    const int wv = threadIdx.x >> 6, lane = threadIdx.x & 63;
    const int q8 = lane >> 4, c = lane & 15;
    const int gw = blockIdx.x * 4 + wv;
    const float T = temp[0];
    const float inv2T2 = 1.0f / (2.0f * T * T);
    const float c2 = 2.0f * inv2T2;

    short8 av[4][8];   // 64 rows x 256 cols bf16 -> 128 VGPRs
    float ar[16];      // -sq[row] * inv2T2 per owned row slot
    int iloaded = -1;

    for (int s = 0; s < UPW; ++s) {
        const int u = gw * UPW + s;
        if (u >= NU) return;

        // decode u -> (i, j), j >= i; C(i) = 128i - i(i-1)/2
        int i = (int)((257.0f - sqrtf(66049.0f - 8.0f * (float)u)) * 0.5f);
        while (128 * i - (i * (i - 1)) / 2 > u) --i;
        while (128 * (i + 1) - ((i + 1) * i) / 2 <= u) ++i;
        const int j = i + (u - (128 * i - (i * (i - 1)) / 2));
        const int rowbase = i * 64, colbase = j * 64;

        if (i != iloaded) {
            iloaded = i;
#pragma unroll
            for (int rt = 0; rt < 4; ++rt) {
                const unsigned short* ap =
                    xb + (size_t)(rowbase + rt * 16 + c) * D + q8 * 8;
#pragma unroll
                for (int kk = 0; kk < 8; ++kk)
                    av[rt][kk] = *(const short8*)(ap + kk * 32);
            }
#pragma unroll
            for (int rt = 0; rt < 4; ++rt)
#pragma unroll
                for (int r = 0; r < 4; ++r)
                    ar[rt * 4 + r] = -sq[rowbase + rt * 16 + q8 * 4 + r] * inv2T2;
        }

        float Sr[16], Mr[16], Sc[4], Mc[4];
#pragma unroll
        for (int k = 0; k < 16; ++k) { Sr[k] = 0.f; Mr[k] = 0.f; }
#pragma unroll
        for (int k = 0; k < 4; ++k) { Sc[k] = 0.f; Mc[k] = 0.f; }

#pragma unroll
        for (int tc = 0; tc < 4; ++tc) {
            const unsigned short* bp =
                xb + (size_t)(colbase + tc * 16 + c) * D + q8 * 8;
            short8 bv[8];
#pragma unroll
            for (int kk = 0; kk < 8; ++kk)
                bv[kk] = *(const short8*)(bp + kk * 32);
            const float bc = -sq[colbase + tc * 16 + c] * inv2T2;

            f32x4 acc[4];
#pragma unroll
            for (int rt = 0; rt < 4; ++rt)
#pragma unroll
                for (int r = 0; r < 4; ++r) acc[rt][r] = 0.0f;

#pragma unroll
            for (int kk = 0; kk < 8; ++kk)
#pragma unroll
                for (int rt = 0; rt < 4; ++rt)
                    acc[rt] = __builtin_amdgcn_mfma_f32_16x16x32_bf16(
                        av[rt][kk], bv[kk], acc[rt], 0, 0, 0);

            // fused epilogue: t = ln k = min((2g - sr - sc)*inv2T2, 0)
#pragma unroll
            for (int rt = 0; rt < 4; ++rt)
#pragma unroll
                for (int r = 0; r < 4; ++r) {
                    float g = acc[rt][r];
                    float t = fminf(fmaf(g, c2, ar[rt * 4 + r]) + bc, 0.0f);
                    float e = __expf(t);
                    float w = e * t;
                    Sr[rt * 4 + r] += e;
                    Mr[rt * 4 + r] += w;
                    Sc[tc] += e;
                    Mc[tc] += w;
                }
        }

        // commit row sums: reduce across the 16 col-lanes (lane bits 0..3)
#pragma unroll
        for (int m = 1; m <= 8; m <<= 1)
#pragma unroll
            for (int k = 0; k < 16; ++k) {
                Sr[k] += __shfl_xor(Sr[k], m, 64);
                Mr[k] += __shfl_xor(Mr[k], m, 64);
            }
        if (c == 0) {
#pragma unroll
            for (int k = 0; k < 16; ++k) {
                int row = rowbase + (k >> 2) * 16 + q8 * 4 + (k & 3);
                atomicAdd(&Sarr[row], Sr[k]);
                atomicAdd(&Larr[row], Mr[k]);
            }
        }

        // commit col sums (symmetric counterpart) for off-diagonal units:
        // reduce across the 4 row-quads (lane bits 4..5)
        if (i != j) {
#pragma unroll
            for (int m = 16; m <= 32; m <<= 1)
#pragma unroll
                for (int k = 0; k < 4; ++k) {
                    Sc[k] += __shfl_xor(Sc[k], m, 64);
                    Mc[k] += __shfl_xor(Mc[k], m, 64);
                }
            if (q8 == 0) {
#pragma unroll
                for (int k = 0; k < 4; ++k) {
                    int col = colbase + k * 16 + c;
                    atomicAdd(&Sarr[col], Sc[k]);
                    atomicAdd(&Larr[col], Mc[k]);
                }
            }
        }
    }
}

// Kernel 2 (merged ctrl+scale): per row H = log(S) - L/S,
// cs = sigmoid(-(H - target)/T); write scaled features + control signal.
__global__ __launch_bounds__(256) void k_finish(const float* __restrict__ x,
                                                const float* __restrict__ Sarr,
                                                const float* __restrict__ Larr,
                                                const float* __restrict__ target,
                                                const float* __restrict__ temp,
                                                float* __restrict__ out) {
    const int gid = blockIdx.x * 256 + threadIdx.x;  // float4 index
    const int row = gid >> 6;                        // 64 float4 per row
    float S = Sarr[row], L = Larr[row];
    float H = __logf(S) - L / S;
    float z = (H - target[0]) / temp[0];
    float cs = 1.0f / (1.0f + __expf(z));
    float4 v = ((const float4*)x)[gid];
    float4 o;
    o.x = v.x * cs; o.y = v.y * cs; o.z = v.z * cs; o.w = v.w * cs;
    ((float4*)out)[gid] = o;
    if ((gid & 63) == 0) out[(size_t)N * D + row] = cs;  // control_signal section
}

extern "C" void kernel_launch(void* const* d_in, const int* in_sizes, int n_in,
                              void* d_out, int out_size, void* d_ws, size_t ws_size,
                              hipStream_t stream) {
    const float* x = (const float*)d_in[0];       // features [4,2048,256]
    const float* target = (const float*)d_in[7];  // target_entropy [1]
    const float* temp = (const float*)d_in[8];    // temperature [1]
    float* out = (float*)d_out;

    float* wsf = (float*)d_ws;
    float* sq = wsf;
    float* Sarr = wsf + N;
    float* Larr = wsf + 2 * N;

    // bf16 copy of X: in ws if it fits, else park it in d_out's first 4 MB
    // (k_finish only writes d_out after k_gram has fully consumed xb)
    const size_t need = 3 * (size_t)N * sizeof(float) + (size_t)N * D * sizeof(unsigned short);
    unsigned short* xb = (ws_size >= need) ? (unsigned short*)(wsf + 3 * N)
                                           : (unsigned short*)d_out;

    k_cvt<<<N / 4, 256, 0, stream>>>(x, xb, sq, Sarr, Larr);
    // NU units, 4 waves/block, UPW units/wave -> 8256/8 = 1032 blocks exactly
    k_gram<<<NU / (4 * UPW), 256, 0, stream>>>(xb, sq, temp, Sarr, Larr);
    k_finish<<<(N * (D / 4)) / 256, 256, 0, stream>>>(x, Sarr, Larr, target, temp, out);
}

// Round 5
// 171.840 us; speedup vs baseline: 1.6206x; 1.6206x over previous
//
#include <hip/hip_runtime.h>

#define N 8192
#define D 256

typedef short short8 __attribute__((ext_vector_type(8)));
typedef float f32x4 __attribute__((ext_vector_type(4)));

__device__ __forceinline__ unsigned short f2bf(float f) {
    unsigned int u = __float_as_uint(f);
    u += 0x7fffu + ((u >> 16) & 1u);   // RNE
    return (unsigned short)(u >> 16);
}
__device__ __forceinline__ float bf2f(unsigned short h) {
    return __uint_as_float(((unsigned int)h) << 16);
}

// async global->LDS, 16B per lane; dst is wave-uniform base, lane i lands at dst + i*16
#define GLDS16(g, l) __builtin_amdgcn_global_load_lds(                      \
    (const __attribute__((address_space(1))) void*)(g),                     \
    (__attribute__((address_space(3))) void*)(l), 16, 0, 0)

// Kernel 0: fp32 -> bf16 pre-conversion + row squared norms (of bf16-rounded
// values, consistent with the MFMA Gram) + zero the S/L accumulators.
__global__ __launch_bounds__(256) void k_cvt(const float* __restrict__ x,
                                             unsigned short* __restrict__ xb,
                                             float* __restrict__ sq,
                                             float* __restrict__ Sarr,
                                             float* __restrict__ Larr) {
    const int wv = threadIdx.x >> 6, lane = threadIdx.x & 63;
    const int row = blockIdx.x * 4 + wv;
    const float4 v = ((const float4*)x)[(size_t)row * 64 + lane];
    unsigned short pa = f2bf(v.x), pb = f2bf(v.y), pc = f2bf(v.z), pd = f2bf(v.w);
    float a = bf2f(pa), b = bf2f(pb), c = bf2f(pc), d = bf2f(pd);
    float s = a * a + b * b + c * c + d * d;
    ((ushort4*)xb)[(size_t)row * 64 + lane] = make_ushort4(pa, pb, pc, pd);
#pragma unroll
    for (int m = 1; m < 64; m <<= 1) s += __shfl_xor(s, m, 64);
    if (lane == 0) {
        sq[row] = s;
        Sarr[row] = 0.0f;
        Larr[row] = 0.0f;
    }
}

// Kernel 1: symmetric Gram, R2 pipeline + diagonal-wrap tile selection.
// Block (i, y): 128 rows (A in regs, 32/wave = 64 VGPR) x col-blocks
// j = (i + k) mod 64 for k in {y, y+8, y+16, y+24} (+ k=32 iff y==7 && i<32).
// B streamed through one 32 KB LDS tile (64 cols x K=256) via global_load_lds
// with 16B-chunk XOR swizzle; 2 barriers per 64-col subtile (R2 cadence).
// Row-sums accumulate in regs across the whole block (one commit); col-sums
// (symmetric transpose contribution) commit per subtile for k != 0.
// Exactly-once coverage: pair of tile-blocks (a,b) with delta=(b-a)%64 is
// covered by (a,delta) row-commit if delta<=32 (k=32 only i<32), else by
// (b,64-delta) col-commit; diagonal k=0 commits rows only.
__global__ __launch_bounds__(256, 3) void k_gram(const unsigned short* __restrict__ xb,
                                                 const float* __restrict__ sq,
                                                 const float* __restrict__ temp,
                                                 float* __restrict__ Sarr,
                                                 float* __restrict__ Larr) {
    __shared__ unsigned short Bs[64 * D];   // 32 KB, 16B-chunk XOR swizzled

    const int tid = threadIdx.x;
    const int wv = tid >> 6, lane = tid & 63;
    const int q8 = lane >> 4, c = lane & 15;
    const int i = blockIdx.x;       // row-block (128 rows)
    const int y = blockIdx.y;       // k-group
    const int rowbase = i * 128;
    const float T = temp[0];
    const float inv2T2 = 1.0f / (2.0f * T * T);
    const float c2 = 2.0f * inv2T2;

    // A fragments in registers: wave wv owns rows rowbase + wv*32 .. +31
    short8 av[2][8];
#pragma unroll
    for (int tr = 0; tr < 2; ++tr) {
        const unsigned short* ap = xb + (size_t)(rowbase + wv * 32 + tr * 16 + c) * D;
#pragma unroll
        for (int kk = 0; kk < 8; ++kk)
            av[tr][kk] = *(const short8*)(ap + kk * 32 + q8 * 8);
    }
    float ar[8];   // premultiplied -sq[row]*inv2T2 per owned row slot
#pragma unroll
    for (int tr = 0; tr < 2; ++tr)
#pragma unroll
        for (int r = 0; r < 4; ++r)
            ar[tr * 4 + r] = -sq[rowbase + wv * 32 + tr * 16 + q8 * 4 + r] * inv2T2;

    // LDS read swizzle precompute
    const int rx = c & 7;
    int rofs[4];
#pragma unroll
    for (int tc = 0; tc < 4; ++tc) rofs[tc] = (tc * 16 + c) * D;

    // staging-source lane decomposition
    const int seg0 = wv * 8;
    const int rhalf = lane >> 5, slot = lane & 31;

    float Sr[8], Mr[8];
#pragma unroll
    for (int k = 0; k < 8; ++k) { Sr[k] = 0.f; Mr[k] = 0.f; }

    const int ntiles = (y == 7 && i < 32) ? 5 : 4;

    for (int t = 0; t < ntiles; ++t) {
        const int kblk = (t < 4) ? (y + 8 * t) : 32;
        const int j = (i + kblk) & 63;
        const bool docol = (kblk != 0);

        for (int sub = 0; sub < 2; ++sub) {
            const int colbase = j * 128 + sub * 64;
            __syncthreads();   // previous subtile's readers done
#pragma unroll
            for (int g2 = 0; g2 < 8; ++g2) {
                int seg = seg0 + g2;
                int row = seg * 2 + rhalf;              // B-col 0..63
                int g = slot ^ (row & 7);
                GLDS16(xb + (size_t)(colbase + row) * D + g * 8, Bs + seg * 512);
            }
            __syncthreads();   // staging complete (vmcnt drained at barrier)

            f32x4 acc[2][4];
#pragma unroll
            for (int tr = 0; tr < 2; ++tr)
#pragma unroll
                for (int tc = 0; tc < 4; ++tc)
#pragma unroll
                    for (int r = 0; r < 4; ++r) acc[tr][tc][r] = 0.0f;

#pragma unroll
            for (int kk = 0; kk < 8; ++kk) {
                short8 bv[4];
#pragma unroll
                for (int tc = 0; tc < 4; ++tc)
                    bv[tc] = *(const short8*)(Bs + rofs[tc] + (((4 * kk + q8) ^ rx) << 3));
#pragma unroll
                for (int tr = 0; tr < 2; ++tr)
#pragma unroll
                    for (int tc = 0; tc < 4; ++tc)
                        acc[tr][tc] = __builtin_amdgcn_mfma_f32_16x16x32_bf16(
                            av[tr][kk], bv[tc], acc[tr][tc], 0, 0, 0);
            }

            float bc[4], Sc[4], Mc[4];
#pragma unroll
            for (int tc = 0; tc < 4; ++tc) {
                bc[tc] = -sq[colbase + tc * 16 + c] * inv2T2;
                Sc[tc] = 0.f; Mc[tc] = 0.f;
            }

            // fused epilogue: t = ln k = min((2g - sr - sc)*inv2T2, 0)
#pragma unroll
            for (int tr = 0; tr < 2; ++tr)
#pragma unroll
                for (int tc = 0; tc < 4; ++tc)
#pragma unroll
                    for (int r = 0; r < 4; ++r) {
                        float g = acc[tr][tc][r];
                        float tt = fminf(fmaf(g, c2, ar[tr * 4 + r]) + bc[tc], 0.0f);
                        float e = __expf(tt);
                        float w = e * tt;
                        Sr[tr * 4 + r] += e;
                        Mr[tr * 4 + r] += w;
                        Sc[tc] += e;
                        Mc[tc] += w;
                    }

            // col-sum commit (transpose contribution): reduce over row-quads
            if (docol) {
#pragma unroll
                for (int m = 16; m <= 32; m <<= 1)
#pragma unroll
                    for (int tc = 0; tc < 4; ++tc) {
                        Sc[tc] += __shfl_xor(Sc[tc], m, 64);
                        Mc[tc] += __shfl_xor(Mc[tc], m, 64);
                    }
                if (q8 == 0) {
#pragma unroll
                    for (int tc = 0; tc < 4; ++tc) {
                        atomicAdd(&Sarr[colbase + tc * 16 + c], Sc[tc]);
                        atomicAdd(&Larr[colbase + tc * 16 + c], Mc[tc]);
                    }
                }
            }
        }
    }

    // row-sum commit: reduce across the 16 col-lanes (lane bits 0..3)
#pragma unroll
    for (int m = 1; m <= 8; m <<= 1)
#pragma unroll
        for (int k = 0; k < 8; ++k) {
            Sr[k] += __shfl_xor(Sr[k], m, 64);
            Mr[k] += __shfl_xor(Mr[k], m, 64);
        }
    if (c == 0) {
#pragma unroll
        for (int k = 0; k < 8; ++k) {
            int row = rowbase + wv * 32 + (k >> 2) * 16 + q8 * 4 + (k & 3);
            atomicAdd(&Sarr[row], Sr[k]);
            atomicAdd(&Larr[row], Mr[k]);
        }
    }
}

// Kernel 2 (merged ctrl+scale): per row H = log(S) - L/S,
// cs = sigmoid(-(H - target)/T); write scaled features + control signal.
__global__ __launch_bounds__(256) void k_finish(const float* __restrict__ x,
                                                const float* __restrict__ Sarr,
                                                const float* __restrict__ Larr,
                                                const float* __restrict__ target,
                                                const float* __restrict__ temp,
                                                float* __restrict__ out) {
    const int gid = blockIdx.x * 256 + threadIdx.x;  // float4 index
    const int row = gid >> 6;                        // 64 float4 per row
    float S = Sarr[row], L = Larr[row];
    float H = __logf(S) - L / S;
    float z = (H - target[0]) / temp[0];
    float cs = 1.0f / (1.0f + __expf(z));
    float4 v = ((const float4*)x)[gid];
    float4 o;
    o.x = v.x * cs; o.y = v.y * cs; o.z = v.z * cs; o.w = v.w * cs;
    ((float4*)out)[gid] = o;
    if ((gid & 63) == 0) out[(size_t)N * D + row] = cs;  // control_signal section
}

extern "C" void kernel_launch(void* const* d_in, const int* in_sizes, int n_in,
                              void* d_out, int out_size, void* d_ws, size_t ws_size,
                              hipStream_t stream) {
    const float* x = (const float*)d_in[0];       // features [4,2048,256]
    const float* target = (const float*)d_in[7];  // target_entropy [1]
    const float* temp = (const float*)d_in[8];    // temperature [1]
    float* out = (float*)d_out;

    float* wsf = (float*)d_ws;
    float* sq = wsf;
    float* Sarr = wsf + N;
    float* Larr = wsf + 2 * N;

    // bf16 copy of X: in ws if it fits, else park it in d_out's first 4 MB
    // (k_finish only writes d_out after k_gram has fully consumed xb)
    const size_t need = 3 * (size_t)N * sizeof(float) + (size_t)N * D * sizeof(unsigned short);
    unsigned short* xb = (ws_size >= need) ? (unsigned short*)(wsf + 3 * N)
                                           : (unsigned short*)d_out;

    k_cvt<<<N / 4, 256, 0, stream>>>(x, xb, sq, Sarr, Larr);
    k_gram<<<dim3(64, 8), 256, 0, stream>>>(xb, sq, temp, Sarr, Larr);
    k_finish<<<(N * (D / 4)) / 256, 256, 0, stream>>>(x, Sarr, Larr, target, temp, out);
}

// Round 6
// 123.209 us; speedup vs baseline: 2.2603x; 1.3947x over previous
//
#include <hip/hip_runtime.h>

#define N 8192
#define D 256

typedef short short8 __attribute__((ext_vector_type(8)));
typedef float f32x4 __attribute__((ext_vector_type(4)));

__device__ __forceinline__ unsigned short f2bf(float f) {
    unsigned int u = __float_as_uint(f);
    u += 0x7fffu + ((u >> 16) & 1u);   // RNE
    return (unsigned short)(u >> 16);
}
__device__ __forceinline__ float bf2f(unsigned short h) {
    return __uint_as_float(((unsigned int)h) << 16);
}

// async global->LDS, 16B per lane; dst is wave-uniform base, lane i lands at dst + i*16
#define GLDS16(g, l) __builtin_amdgcn_global_load_lds(                      \
    (const __attribute__((address_space(1))) void*)(g),                     \
    (__attribute__((address_space(3))) void*)(l), 16, 0, 0)

// Kernel 0: fp32 -> bf16 pre-conversion + row squared norms (of bf16-rounded
// values, consistent with the MFMA Gram) + zero the S/L accumulators.
__global__ __launch_bounds__(256) void k_cvt(const float* __restrict__ x,
                                             unsigned short* __restrict__ xb,
                                             float* __restrict__ sq,
                                             float* __restrict__ Sarr,
                                             float* __restrict__ Larr) {
    const int wv = threadIdx.x >> 6, lane = threadIdx.x & 63;
    const int row = blockIdx.x * 4 + wv;
    const float4 v = ((const float4*)x)[(size_t)row * 64 + lane];
    unsigned short pa = f2bf(v.x), pb = f2bf(v.y), pc = f2bf(v.z), pd = f2bf(v.w);
    float a = bf2f(pa), b = bf2f(pb), c = bf2f(pc), d = bf2f(pd);
    float s = a * a + b * b + c * c + d * d;
    ((ushort4*)xb)[(size_t)row * 64 + lane] = make_ushort4(pa, pb, pc, pd);
#pragma unroll
    for (int m = 1; m < 64; m <<= 1) s += __shfl_xor(s, m, 64);
    if (lane == 0) {
        sq[row] = s;
        Sarr[row] = 0.0f;
        Larr[row] = 0.0f;
    }
}

// Kernel 1: R2 structure + software-pipelined staging.
// Block (i,y): 128 rows (A in regs, 32/wave) x contiguous 512-col chunk,
// processed as 16 half-tiles of 32 cols, ping-ponged between two 16 KB LDS
// halves. ONE barrier per half-tile; the NEXT half-tile's global_load_lds is
// issued immediately AFTER the barrier, so its L2 latency is hidden behind
// the current half-tile's 32 MFMA + epilogue (vs R2: issued right before the
// drain). Contiguous col sweep preserved for L2 locality (R5 lesson).
__global__ __launch_bounds__(256, 3) void k_gram(const unsigned short* __restrict__ xb,
                                                 const float* __restrict__ sq,
                                                 const float* __restrict__ temp,
                                                 float* __restrict__ Sarr,
                                                 float* __restrict__ Larr) {
    __shared__ unsigned short Bs[2][32 * D];   // 2 x 16 KB, 16B-chunk XOR swizzled

    const int tid = threadIdx.x;
    const int wv = tid >> 6, lane = tid & 63;
    const int q8 = lane >> 4, c = lane & 15;
    const int rowbase = blockIdx.x * 128;
    const int ybase = blockIdx.y * 512;
    const float T = temp[0];
    const float inv2T2 = 1.0f / (2.0f * T * T);
    const float c2 = 2.0f * inv2T2;

    // A fragments in registers: wave wv owns rows rowbase + wv*32 .. +31
    short8 av[2][8];
#pragma unroll
    for (int tr = 0; tr < 2; ++tr) {
        const unsigned short* ap = xb + (size_t)(rowbase + wv * 32 + tr * 16 + c) * D;
#pragma unroll
        for (int kk = 0; kk < 8; ++kk)
            av[tr][kk] = *(const short8*)(ap + kk * 32 + q8 * 8);
    }
    float ar[8];   // premultiplied -sq[row]*inv2T2 per owned row slot
#pragma unroll
    for (int tr = 0; tr < 2; ++tr)
#pragma unroll
        for (int r = 0; r < 4; ++r)
            ar[tr * 4 + r] = -sq[rowbase + wv * 32 + tr * 16 + q8 * 4 + r] * inv2T2;

    // LDS read swizzle precompute (B-rows this lane touches: tc*16 + c)
    const int rx = c & 7;
    int rofs[2];
#pragma unroll
    for (int tc = 0; tc < 2; ++tc) rofs[tc] = (tc * 16 + c) * D;

    // staging decomposition: 16 KB/half-tile = 16 segs of 1 KB (2 B-rows);
    // wave wv stages segs wv*4 .. wv*4+3; lane -> (row parity, 16B slot)
    const int seg0 = wv * 4;
    const int rhalf = lane >> 5, slot = lane & 31;

    float Sr[8], Mr[8];
#pragma unroll
    for (int k = 0; k < 8; ++k) { Sr[k] = 0.f; Mr[k] = 0.f; }

    // prologue: stage half-tile 0 into buffer 0
#pragma unroll
    for (int g2 = 0; g2 < 4; ++g2) {
        int seg = seg0 + g2;
        int row = seg * 2 + rhalf;                  // B-col 0..31 within half-tile
        int g = slot ^ (row & 7);
        GLDS16(xb + (size_t)(ybase + row) * D + g * 8, &Bs[0][0] + seg * 512);
    }

    for (int ht = 0; ht < 16; ++ht) {
        const int colbase = ybase + ht * 32;
        const int cur = ht & 1;

        // drains this wave's stage of half-tile ht (issued a full compute
        // phase ago); also fences all waves' reads of buffer cur from ht-2.
        __syncthreads();

        if (ht < 15) {
            const int nb = colbase + 32;
#pragma unroll
            for (int g2 = 0; g2 < 4; ++g2) {
                int seg = seg0 + g2;
                int row = seg * 2 + rhalf;
                int g = slot ^ (row & 7);
                GLDS16(xb + (size_t)(nb + row) * D + g * 8, &Bs[cur ^ 1][0] + seg * 512);
            }
        }

        // column norms for this half-tile (issued early; used after the MFMAs)
        float bc[2];
#pragma unroll
        for (int tc = 0; tc < 2; ++tc)
            bc[tc] = -sq[colbase + tc * 16 + c] * inv2T2;

        f32x4 acc[2][2];
#pragma unroll
        for (int tr = 0; tr < 2; ++tr)
#pragma unroll
            for (int tc = 0; tc < 2; ++tc)
#pragma unroll
                for (int r = 0; r < 4; ++r) acc[tr][tc][r] = 0.0f;

#pragma unroll
        for (int kk = 0; kk < 8; ++kk) {
            short8 bv[2];
#pragma unroll
            for (int tc = 0; tc < 2; ++tc)
                bv[tc] = *(const short8*)(&Bs[cur][0] + rofs[tc] + (((4 * kk + q8) ^ rx) << 3));
#pragma unroll
            for (int tr = 0; tr < 2; ++tr)
#pragma unroll
                for (int tc = 0; tc < 2; ++tc)
                    acc[tr][tc] = __builtin_amdgcn_mfma_f32_16x16x32_bf16(
                        av[tr][kk], bv[tc], acc[tr][tc], 0, 0, 0);
        }

        // fused epilogue: t = ln k = min((2g - sr - sc)*inv2T2, 0)
#pragma unroll
        for (int tr = 0; tr < 2; ++tr)
#pragma unroll
            for (int tc = 0; tc < 2; ++tc)
#pragma unroll
                for (int r = 0; r < 4; ++r) {
                    float g = acc[tr][tc][r];
                    float tt = fminf(fmaf(g, c2, ar[tr * 4 + r]) + bc[tc], 0.0f);
                    float e = __expf(tt);
                    Sr[tr * 4 + r] += e;
                    Mr[tr * 4 + r] = fmaf(e, tt, Mr[tr * 4 + r]);
                }
    }

    // row-sum commit: reduce across the 16 col-lanes (lane bits 0..3)
#pragma unroll
    for (int m = 1; m <= 8; m <<= 1)
#pragma unroll
        for (int k = 0; k < 8; ++k) {
            Sr[k] += __shfl_xor(Sr[k], m, 64);
            Mr[k] += __shfl_xor(Mr[k], m, 64);
        }
    if (c == 0) {
#pragma unroll
        for (int k = 0; k < 8; ++k) {
            int row = rowbase + wv * 32 + (k >> 2) * 16 + q8 * 4 + (k & 3);
            atomicAdd(&Sarr[row], Sr[k]);
            atomicAdd(&Larr[row], Mr[k]);
        }
    }
}

// Kernel 2 (merged ctrl+scale): per row H = log(S) - L/S,
// cs = sigmoid(-(H - target)/T); write scaled features + control signal.
__global__ __launch_bounds__(256) void k_finish(const float* __restrict__ x,
                                                const float* __restrict__ Sarr,
                                                const float* __restrict__ Larr,
                                                const float* __restrict__ target,
                                                const float* __restrict__ temp,
                                                float* __restrict__ out) {
    const int gid = blockIdx.x * 256 + threadIdx.x;  // float4 index
    const int row = gid >> 6;                        // 64 float4 per row
    float S = Sarr[row], L = Larr[row];
    float H = __logf(S) - L / S;
    float z = (H - target[0]) / temp[0];
    float cs = 1.0f / (1.0f + __expf(z));
    float4 v = ((const float4*)x)[gid];
    float4 o;
    o.x = v.x * cs; o.y = v.y * cs; o.z = v.z * cs; o.w = v.w * cs;
    ((float4*)out)[gid] = o;
    if ((gid & 63) == 0) out[(size_t)N * D + row] = cs;  // control_signal section
}

extern "C" void kernel_launch(void* const* d_in, const int* in_sizes, int n_in,
                              void* d_out, int out_size, void* d_ws, size_t ws_size,
                              hipStream_t stream) {
    const float* x = (const float*)d_in[0];       // features [4,2048,256]
    const float* target = (const float*)d_in[7];  // target_entropy [1]
    const float* temp = (const float*)d_in[8];    // temperature [1]
    float* out = (float*)d_out;

    float* wsf = (float*)d_ws;
    float* sq = wsf;
    float* Sarr = wsf + N;
    float* Larr = wsf + 2 * N;

    // bf16 copy of X: in ws if it fits, else park it in d_out's first 4 MB
    // (k_finish only writes d_out after k_gram has fully consumed xb)
    const size_t need = 3 * (size_t)N * sizeof(float) + (size_t)N * D * sizeof(unsigned short);
    unsigned short* xb = (ws_size >= need) ? (unsigned short*)(wsf + 3 * N)
                                           : (unsigned short*)d_out;

    k_cvt<<<N / 4, 256, 0, stream>>>(x, xb, sq, Sarr, Larr);
    k_gram<<<dim3(64, 16), 256, 0, stream>>>(xb, sq, temp, Sarr, Larr);
    k_finish<<<(N * (D / 4)) / 256, 256, 0, stream>>>(x, Sarr, Larr, target, temp, out);
}

// Round 7
// 119.297 us; speedup vs baseline: 2.3344x; 1.0328x over previous
//
#include <hip/hip_runtime.h>

#define N 8192
#define D 256

typedef short short8 __attribute__((ext_vector_type(8)));
typedef float f32x4 __attribute__((ext_vector_type(4)));

__device__ __forceinline__ unsigned short f2bf(float f) {
    unsigned int u = __float_as_uint(f);
    u += 0x7fffu + ((u >> 16) & 1u);   // RNE
    return (unsigned short)(u >> 16);
}
__device__ __forceinline__ float bf2f(unsigned short h) {
    return __uint_as_float(((unsigned int)h) << 16);
}

// async global->LDS, 16B per lane; dst is wave-uniform base, lane i lands at dst + i*16
#define GLDS16(g, l) __builtin_amdgcn_global_load_lds(                      \
    (const __attribute__((address_space(1))) void*)(g),                     \
    (__attribute__((address_space(3))) void*)(l), 16, 0, 0)

// Kernel 0: fp32 -> bf16 pre-conversion + row squared norms (of bf16-rounded
// values, consistent with the MFMA Gram) + zero the S/L accumulators.
__global__ __launch_bounds__(256) void k_cvt(const float* __restrict__ x,
                                             unsigned short* __restrict__ xb,
                                             float* __restrict__ sq,
                                             float* __restrict__ Sarr,
                                             float* __restrict__ Larr) {
    const int wv = threadIdx.x >> 6, lane = threadIdx.x & 63;
    const int row = blockIdx.x * 4 + wv;
    const float4 v = ((const float4*)x)[(size_t)row * 64 + lane];
    unsigned short pa = f2bf(v.x), pb = f2bf(v.y), pc = f2bf(v.z), pd = f2bf(v.w);
    float a = bf2f(pa), b = bf2f(pb), c = bf2f(pc), d = bf2f(pd);
    float s = a * a + b * b + c * c + d * d;
    ((ushort4*)xb)[(size_t)row * 64 + lane] = make_ushort4(pa, pb, pc, pd);
#pragma unroll
    for (int m = 1; m < 64; m <<= 1) s += __shfl_xor(s, m, 64);
    if (lane == 0) {
        sq[row] = s;
        Sarr[row] = 0.0f;
        Larr[row] = 0.0f;
    }
}

// Kernel 1: R6 pipeline + SCREENED epilogue.
// All constants pre-scaled by log2(e) so the kernel value is exp2(t2),
// t2 = c2*g + ar + bc (t2 = log2e * ln k). Per half-tile, a conservative
// upper bound  c2*max(g) + max(ar) + max(bc)  decides (wave-uniformly via
// __any) whether ANY element could exceed exp2(-115) ~ 1e-35; if not, the
// 16-element exp epilogue is skipped entirely (contributes exactly 0 in
// fp32 -- the reference's own arithmetic underflows identically).
// Diagonal-touching tiles (~1%) take the exact slow path -> absmax stays 0.
__global__ __launch_bounds__(256, 3) void k_gram(const unsigned short* __restrict__ xb,
                                                 const float* __restrict__ sq,
                                                 const float* __restrict__ temp,
                                                 float* __restrict__ Sarr,
                                                 float* __restrict__ Larr) {
    __shared__ unsigned short Bs[2][32 * D];   // 2 x 16 KB, 16B-chunk XOR swizzled

    const int tid = threadIdx.x;
    const int wv = tid >> 6, lane = tid & 63;
    const int q8 = lane >> 4, c = lane & 15;
    const int rowbase = blockIdx.x * 128;
    const int ybase = blockIdx.y * 512;
    const float T = temp[0];
    const float LOG2E = 1.44269504f;
    const float s2 = -LOG2E / (2.0f * T * T);   // t2 = -(d2) * |s2| ... sign folded
    const float c2 = -2.0f * s2;                // coeff of g (positive)

    // A fragments in registers: wave wv owns rows rowbase + wv*32 .. +31
    short8 av[2][8];
#pragma unroll
    for (int tr = 0; tr < 2; ++tr) {
        const unsigned short* ap = xb + (size_t)(rowbase + wv * 32 + tr * 16 + c) * D;
#pragma unroll
        for (int kk = 0; kk < 8; ++kk)
            av[tr][kk] = *(const short8*)(ap + kk * 32 + q8 * 8);
    }
    float ar[8];   // sq[row] * s2  (log2-scaled, negative)
#pragma unroll
    for (int tr = 0; tr < 2; ++tr)
#pragma unroll
        for (int r = 0; r < 4; ++r)
            ar[tr * 4 + r] = sq[rowbase + wv * 32 + tr * 16 + q8 * 4 + r] * s2;
    float armax = ar[0];
#pragma unroll
    for (int k = 1; k < 8; ++k) armax = fmaxf(armax, ar[k]);

    // LDS read swizzle precompute (B-rows this lane touches: tc*16 + c)
    const int rx = c & 7;
    int rofs[2];
#pragma unroll
    for (int tc = 0; tc < 2; ++tc) rofs[tc] = (tc * 16 + c) * D;

    // staging decomposition: 16 KB/half-tile = 16 segs of 1 KB (2 B-rows);
    // wave wv stages segs wv*4 .. wv*4+3; lane -> (row parity, 16B slot)
    const int seg0 = wv * 4;
    const int rhalf = lane >> 5, slot = lane & 31;

    float Sr[8], Mr[8];
#pragma unroll
    for (int k = 0; k < 8; ++k) { Sr[k] = 0.f; Mr[k] = 0.f; }

    // prologue: stage half-tile 0 into buffer 0
#pragma unroll
    for (int g2 = 0; g2 < 4; ++g2) {
        int seg = seg0 + g2;
        int row = seg * 2 + rhalf;
        int g = slot ^ (row & 7);
        GLDS16(xb + (size_t)(ybase + row) * D + g * 8, &Bs[0][0] + seg * 512);
    }

    for (int ht = 0; ht < 16; ++ht) {
        const int colbase = ybase + ht * 32;
        const int cur = ht & 1;

        __syncthreads();   // drains stage of ht; fences buffer reuse

        if (ht < 15) {
            const int nb = colbase + 32;
#pragma unroll
            for (int g2 = 0; g2 < 4; ++g2) {
                int seg = seg0 + g2;
                int row = seg * 2 + rhalf;
                int g = slot ^ (row & 7);
                GLDS16(xb + (size_t)(nb + row) * D + g * 8, &Bs[cur ^ 1][0] + seg * 512);
            }
        }

        float bc[2];
#pragma unroll
        for (int tc = 0; tc < 2; ++tc)
            bc[tc] = sq[colbase + tc * 16 + c] * s2;
        const float bcmax = fmaxf(bc[0], bc[1]);

        f32x4 acc[2][2];
#pragma unroll
        for (int tr = 0; tr < 2; ++tr)
#pragma unroll
            for (int tc = 0; tc < 2; ++tc)
#pragma unroll
                for (int r = 0; r < 4; ++r) acc[tr][tc][r] = 0.0f;

#pragma unroll
        for (int kk = 0; kk < 8; ++kk) {
            short8 bv[2];
#pragma unroll
            for (int tc = 0; tc < 2; ++tc)
                bv[tc] = *(const short8*)(&Bs[cur][0] + rofs[tc] + (((4 * kk + q8) ^ rx) << 3));
#pragma unroll
            for (int tr = 0; tr < 2; ++tr)
#pragma unroll
                for (int tc = 0; tc < 2; ++tc)
                    acc[tr][tc] = __builtin_amdgcn_mfma_f32_16x16x32_bf16(
                        av[tr][kk], bv[tc], acc[tr][tc], 0, 0, 0);
        }

        // ---- screen: conservative upper bound on t2 over this lane's tile ----
        float gmax = acc[0][0][0];
#pragma unroll
        for (int tr = 0; tr < 2; ++tr)
#pragma unroll
            for (int tc = 0; tc < 2; ++tc)
#pragma unroll
                for (int r = 0; r < 4; ++r) gmax = fmaxf(gmax, acc[tr][tc][r]);
        const float bound = fmaf(gmax, c2, armax + bcmax);

        if (__any(bound >= -115.0f)) {
            // exact slow path (diagonal-touching tiles, ~1%)
#pragma unroll
            for (int tr = 0; tr < 2; ++tr)
#pragma unroll
                for (int tc = 0; tc < 2; ++tc)
#pragma unroll
                    for (int r = 0; r < 4; ++r) {
                        float g = acc[tr][tc][r];
                        float t2 = fminf(fmaf(g, c2, ar[tr * 4 + r] + bc[tc]), 0.0f);
                        float e = __builtin_amdgcn_exp2f(t2);
                        Sr[tr * 4 + r] += e;
                        Mr[tr * 4 + r] = fmaf(e, t2, Mr[tr * 4 + r]);
                    }
        }
        // else: every kernel value underflows fp32 -> contributes exactly 0
    }

    // row-sum commit: reduce across the 16 col-lanes (lane bits 0..3)
#pragma unroll
    for (int m = 1; m <= 8; m <<= 1)
#pragma unroll
        for (int k = 0; k < 8; ++k) {
            Sr[k] += __shfl_xor(Sr[k], m, 64);
            Mr[k] += __shfl_xor(Mr[k], m, 64);
        }
    if (c == 0) {
        const float LN2 = 0.69314718f;   // Mr holds sum e*log2(k); L = ln-scale
#pragma unroll
        for (int k = 0; k < 8; ++k) {
            int row = rowbase + wv * 32 + (k >> 2) * 16 + q8 * 4 + (k & 3);
            atomicAdd(&Sarr[row], Sr[k]);
            atomicAdd(&Larr[row], Mr[k] * LN2);
        }
    }
}

// Kernel 2 (merged ctrl+scale): per row H = log(S) - L/S,
// cs = sigmoid(-(H - target)/T); write scaled features + control signal.
__global__ __launch_bounds__(256) void k_finish(const float* __restrict__ x,
                                                const float* __restrict__ Sarr,
                                                const float* __restrict__ Larr,
                                                const float* __restrict__ target,
                                                const float* __restrict__ temp,
                                                float* __restrict__ out) {
    const int gid = blockIdx.x * 256 + threadIdx.x;  // float4 index
    const int row = gid >> 6;                        // 64 float4 per row
    float S = Sarr[row], L = Larr[row];
    float H = __logf(S) - L / S;
    float z = (H - target[0]) / temp[0];
    float cs = 1.0f / (1.0f + __expf(z));
    float4 v = ((const float4*)x)[gid];
    float4 o;
    o.x = v.x * cs; o.y = v.y * cs; o.z = v.z * cs; o.w = v.w * cs;
    ((float4*)out)[gid] = o;
    if ((gid & 63) == 0) out[(size_t)N * D + row] = cs;  // control_signal section
}

extern "C" void kernel_launch(void* const* d_in, const int* in_sizes, int n_in,
                              void* d_out, int out_size, void* d_ws, size_t ws_size,
                              hipStream_t stream) {
    const float* x = (const float*)d_in[0];       // features [4,2048,256]
    const float* target = (const float*)d_in[7];  // target_entropy [1]
    const float* temp = (const float*)d_in[8];    // temperature [1]
    float* out = (float*)d_out;

    float* wsf = (float*)d_ws;
    float* sq = wsf;
    float* Sarr = wsf + N;
    float* Larr = wsf + 2 * N;

    // bf16 copy of X: in ws if it fits, else park it in d_out's first 4 MB
    // (k_finish only writes d_out after k_gram has fully consumed xb)
    const size_t need = 3 * (size_t)N * sizeof(float) + (size_t)N * D * sizeof(unsigned short);
    unsigned short* xb = (ws_size >= need) ? (unsigned short*)(wsf + 3 * N)
                                           : (unsigned short*)d_out;

    k_cvt<<<N / 4, 256, 0, stream>>>(x, xb, sq, Sarr, Larr);
    k_gram<<<dim3(64, 16), 256, 0, stream>>>(xb, sq, temp, Sarr, Larr);
    k_finish<<<(N * (D / 4)) / 256, 256, 0, stream>>>(x, Sarr, Larr, target, temp, out);
}

// Round 8
// 116.656 us; speedup vs baseline: 2.3872x; 1.0226x over previous
//
#include <hip/hip_runtime.h>

#define N 8192
#define D 256

typedef short short8 __attribute__((ext_vector_type(8)));
typedef float f32x4 __attribute__((ext_vector_type(4)));

__device__ __forceinline__ unsigned short f2bf(float f) {
    unsigned int u = __float_as_uint(f);
    u += 0x7fffu + ((u >> 16) & 1u);   // RNE
    return (unsigned short)(u >> 16);
}
__device__ __forceinline__ float bf2f(unsigned short h) {
    return __uint_as_float(((unsigned int)h) << 16);
}

// async global->LDS, 16B per lane; dst is wave-uniform base, lane i lands at dst + i*16
#define GLDS16(g, l) __builtin_amdgcn_global_load_lds(                      \
    (const __attribute__((address_space(1))) void*)(g),                     \
    (__attribute__((address_space(3))) void*)(l), 16, 0, 0)

// Kernel 0: fp32 -> bf16 pre-conversion + row squared norms (of bf16-rounded
// values, consistent with the MFMA Gram) + zero the S/L accumulators.
__global__ __launch_bounds__(256) void k_cvt(const float* __restrict__ x,
                                             unsigned short* __restrict__ xb,
                                             float* __restrict__ sq,
                                             float* __restrict__ Sarr,
                                             float* __restrict__ Larr) {
    const int wv = threadIdx.x >> 6, lane = threadIdx.x & 63;
    const int row = blockIdx.x * 4 + wv;
    const float4 v = ((const float4*)x)[(size_t)row * 64 + lane];
    unsigned short pa = f2bf(v.x), pb = f2bf(v.y), pc = f2bf(v.z), pd = f2bf(v.w);
    float a = bf2f(pa), b = bf2f(pb), c = bf2f(pc), d = bf2f(pd);
    float s = a * a + b * b + c * c + d * d;
    ((ushort4*)xb)[(size_t)row * 64 + lane] = make_ushort4(pa, pb, pc, pd);
#pragma unroll
    for (int m = 1; m < 64; m <<= 1) s += __shfl_xor(s, m, 64);
    if (lane == 0) {
        sq[row] = s;
        Sarr[row] = 0.0f;
        Larr[row] = 0.0f;
    }
}

// Kernel 1: R7 pipeline with 64 ROWS PER WAVE (256-row blocks) to halve the
// LDS-read traffic (B fragments amortize over 2x rows). A (64 rows x K=256)
// = 128 VGPRs per wave, loaded ONCE in straight-line code (R4's spill came
// from conditional reload inside a dynamic loop -- avoided here). Per-tc
// accumulator (16 regs) keeps peak pressure ~205 VGPR under the 256 budget
// of __launch_bounds__(256,2). Grid (32,16) = 512 blocks = exactly 2/CU.
// Ping-pong staging + screened exp2 epilogue identical to R7.
__global__ __launch_bounds__(256, 2) void k_gram(const unsigned short* __restrict__ xb,
                                                 const float* __restrict__ sq,
                                                 const float* __restrict__ temp,
                                                 float* __restrict__ Sarr,
                                                 float* __restrict__ Larr) {
    __shared__ unsigned short Bs[2][32 * D];   // 2 x 16 KB, 16B-chunk XOR swizzled

    const int tid = threadIdx.x;
    const int wv = tid >> 6, lane = tid & 63;
    const int q8 = lane >> 4, c = lane & 15;
    const int rowbase = blockIdx.x * 256;
    const int ybase = blockIdx.y * 512;
    const float T = temp[0];
    const float LOG2E = 1.44269504f;
    const float s2 = -LOG2E / (2.0f * T * T);   // log2-scaled; t2 = c2*g + ar + bc
    const float c2 = -2.0f * s2;

    // A fragments in registers: wave wv owns rows rowbase + wv*64 .. +63
    short8 av[4][8];
#pragma unroll
    for (int tr = 0; tr < 4; ++tr) {
        const unsigned short* ap = xb + (size_t)(rowbase + wv * 64 + tr * 16 + c) * D;
#pragma unroll
        for (int kk = 0; kk < 8; ++kk)
            av[tr][kk] = *(const short8*)(ap + kk * 32 + q8 * 8);
    }
    float ar[16];   // sq[row] * s2 (negative)
#pragma unroll
    for (int tr = 0; tr < 4; ++tr)
#pragma unroll
        for (int r = 0; r < 4; ++r)
            ar[tr * 4 + r] = sq[rowbase + wv * 64 + tr * 16 + q8 * 4 + r] * s2;
    float armax = ar[0];
#pragma unroll
    for (int k = 1; k < 16; ++k) armax = fmaxf(armax, ar[k]);

    // LDS read swizzle precompute (B-rows this lane touches: tc*16 + c)
    const int rx = c & 7;
    int rofs[2];
#pragma unroll
    for (int tc = 0; tc < 2; ++tc) rofs[tc] = (tc * 16 + c) * D;

    // staging decomposition: 16 KB/half-tile = 16 segs of 1 KB (2 B-cols);
    // wave wv stages segs wv*4 .. wv*4+3
    const int seg0 = wv * 4;
    const int rhalf = lane >> 5, slot = lane & 31;

    float Sr[16], Mr[16];
#pragma unroll
    for (int k = 0; k < 16; ++k) { Sr[k] = 0.f; Mr[k] = 0.f; }

    // prologue: stage half-tile 0 into buffer 0
#pragma unroll
    for (int g2 = 0; g2 < 4; ++g2) {
        int seg = seg0 + g2;
        int row = seg * 2 + rhalf;
        int g = slot ^ (row & 7);
        GLDS16(xb + (size_t)(ybase + row) * D + g * 8, &Bs[0][0] + seg * 512);
    }

    for (int ht = 0; ht < 16; ++ht) {
        const int colbase = ybase + ht * 32;
        const int cur = ht & 1;

        __syncthreads();   // drains stage of ht; fences buffer reuse

        if (ht < 15) {
            const int nb = colbase + 32;
#pragma unroll
            for (int g2 = 0; g2 < 4; ++g2) {
                int seg = seg0 + g2;
                int row = seg * 2 + rhalf;
                int g = slot ^ (row & 7);
                GLDS16(xb + (size_t)(nb + row) * D + g * 8, &Bs[cur ^ 1][0] + seg * 512);
            }
        }

#pragma unroll
        for (int tc = 0; tc < 2; ++tc) {
            const float bc = sq[colbase + tc * 16 + c] * s2;

            f32x4 acc[4];
#pragma unroll
            for (int tr = 0; tr < 4; ++tr)
#pragma unroll
                for (int r = 0; r < 4; ++r) acc[tr][r] = 0.0f;

#pragma unroll
            for (int kk = 0; kk < 8; ++kk) {
                short8 bv = *(const short8*)(&Bs[cur][0] + rofs[tc] +
                                             (((4 * kk + q8) ^ rx) << 3));
#pragma unroll
                for (int tr = 0; tr < 4; ++tr)
                    acc[tr] = __builtin_amdgcn_mfma_f32_16x16x32_bf16(
                        av[tr][kk], bv, acc[tr], 0, 0, 0);
            }

            // screen: conservative upper bound on t2 over this lane's 16 elems
            float gmax = acc[0][0];
#pragma unroll
            for (int tr = 0; tr < 4; ++tr)
#pragma unroll
                for (int r = 0; r < 4; ++r) gmax = fmaxf(gmax, acc[tr][r]);
            const float bound = fmaf(gmax, c2, armax + bc);

            if (__any(bound >= -115.0f)) {
                // exact slow path (diagonal-touching tiles, ~1%)
#pragma unroll
                for (int tr = 0; tr < 4; ++tr)
#pragma unroll
                    for (int r = 0; r < 4; ++r) {
                        float g = acc[tr][r];
                        float t2 = fminf(fmaf(g, c2, ar[tr * 4 + r] + bc), 0.0f);
                        float e = __builtin_amdgcn_exp2f(t2);
                        Sr[tr * 4 + r] += e;
                        Mr[tr * 4 + r] = fmaf(e, t2, Mr[tr * 4 + r]);
                    }
            }
            // else: all values underflow fp32 -> contribute exactly 0
        }
    }

    // row-sum commit: reduce across the 16 col-lanes (lane bits 0..3)
#pragma unroll
    for (int m = 1; m <= 8; m <<= 1)
#pragma unroll
        for (int k = 0; k < 16; ++k) {
            Sr[k] += __shfl_xor(Sr[k], m, 64);
            Mr[k] += __shfl_xor(Mr[k], m, 64);
        }
    if (c == 0) {
        const float LN2 = 0.69314718f;   // Mr holds sum e*log2(k); rescale to ln
#pragma unroll
        for (int k = 0; k < 16; ++k) {
            int row = rowbase + wv * 64 + (k >> 2) * 16 + q8 * 4 + (k & 3);
            atomicAdd(&Sarr[row], Sr[k]);
            atomicAdd(&Larr[row], Mr[k] * LN2);
        }
    }
}

// Kernel 2 (merged ctrl+scale): per row H = log(S) - L/S,
// cs = sigmoid(-(H - target)/T); write scaled features + control signal.
__global__ __launch_bounds__(256) void k_finish(const float* __restrict__ x,
                                                const float* __restrict__ Sarr,
                                                const float* __restrict__ Larr,
                                                const float* __restrict__ target,
                                                const float* __restrict__ temp,
                                                float* __restrict__ out) {
    const int gid = blockIdx.x * 256 + threadIdx.x;  // float4 index
    const int row = gid >> 6;                        // 64 float4 per row
    float S = Sarr[row], L = Larr[row];
    float H = __logf(S) - L / S;
    float z = (H - target[0]) / temp[0];
    float cs = 1.0f / (1.0f + __expf(z));
    float4 v = ((const float4*)x)[gid];
    float4 o;
    o.x = v.x * cs; o.y = v.y * cs; o.z = v.z * cs; o.w = v.w * cs;
    ((float4*)out)[gid] = o;
    if ((gid & 63) == 0) out[(size_t)N * D + row] = cs;  // control_signal section
}

extern "C" void kernel_launch(void* const* d_in, const int* in_sizes, int n_in,
                              void* d_out, int out_size, void* d_ws, size_t ws_size,
                              hipStream_t stream) {
    const float* x = (const float*)d_in[0];       // features [4,2048,256]
    const float* target = (const float*)d_in[7];  // target_entropy [1]
    const float* temp = (const float*)d_in[8];    // temperature [1]
    float* out = (float*)d_out;

    float* wsf = (float*)d_ws;
    float* sq = wsf;
    float* Sarr = wsf + N;
    float* Larr = wsf + 2 * N;

    // bf16 copy of X: in ws if it fits, else park it in d_out's first 4 MB
    // (k_finish only writes d_out after k_gram has fully consumed xb)
    const size_t need = 3 * (size_t)N * sizeof(float) + (size_t)N * D * sizeof(unsigned short);
    unsigned short* xb = (ws_size >= need) ? (unsigned short*)(wsf + 3 * N)
                                           : (unsigned short*)d_out;

    k_cvt<<<N / 4, 256, 0, stream>>>(x, xb, sq, Sarr, Larr);
    k_gram<<<dim3(32, 16), 256, 0, stream>>>(xb, sq, temp, Sarr, Larr);
    k_finish<<<(N * (D / 4)) / 256, 256, 0, stream>>>(x, Sarr, Larr, target, temp, out);
}